// Round 8
// baseline (50.913 us; speedup 1.0000x reference)
//
#include <hip/hip_runtime.h>

#define LOG2E 1.44269504088896340736f
#define LN2   0.69314718055994530942f

typedef __attribute__((ext_vector_type(8))) short bf16x8;
typedef __attribute__((ext_vector_type(4))) float f32x4;
typedef __attribute__((ext_vector_type(16))) float f32x16;

// ws float offsets
#define WS_MUP  0        // 8192 x 16 u32 : packed [mu_hi(16)|mu_lo(16)] bf16
#define WS_SPT  131072   // 8192 x 16 u32 : packed [sp'_hi|sp'_lo], sp' = log2e*sp
#define WS_AV1  262144   // 8192 f32
#define WS_P1   270336   // 64 x 8192 f32 partials, pass 1
#define WS_P2   794624   // 64 x 8192 f32 partials, pass 2

__device__ __forceinline__ unsigned short bf16_rne(float x) {
  unsigned int u = __float_as_uint(x);
  u = u + 0x7FFFu + ((u >> 16) & 1u);
  return (unsigned short)(u >> 16);
}
__device__ __forceinline__ float bf16f(unsigned short h) {
  return __uint_as_float(((unsigned int)h) << 16);
}
__device__ __forceinline__ float fast_exp2(float x) {
#if __has_builtin(__builtin_amdgcn_exp2f)
  return __builtin_amdgcn_exp2f(x);
#else
  return exp2f(x);
#endif
}
__device__ __forceinline__ float fast_log2(float x) {
#if __has_builtin(__builtin_amdgcn_logf)
  return __builtin_amdgcn_logf(x);
#else
  return log2f(x);
#endif
}

__device__ __forceinline__ void pack_row(const float* v, unsigned int* buf) {
#pragma unroll
  for (int k = 0; k < 16; k += 2) {
    unsigned short h0 = bf16_rne(v[k]);
    unsigned short h1 = bf16_rne(v[k + 1]);
    float l0 = v[k] - bf16f(h0);
    float l1 = v[k + 1] - bf16f(h1);
    buf[k >> 1] = (unsigned int)h0 | ((unsigned int)h1 << 16);
    buf[8 + (k >> 1)] = (unsigned int)bf16_rne(l0) | ((unsigned int)bf16_rne(l1) << 16);
  }
}

__global__ __launch_bounds__(256) void k_prep(
    const float* __restrict__ particles, const float* __restrict__ lw,
    const float* __restrict__ sp,
    const float* __restrict__ A, const float* __restrict__ B,
    unsigned int* __restrict__ muP, unsigned int* __restrict__ spT,
    float* __restrict__ av1) {
  int j = blockIdx.x * 256 + threadIdx.x;
  float x[24];
  {
    const float4* p4 = (const float4*)(particles + (size_t)j * 24);
#pragma unroll
    for (int q = 0; q < 6; ++q) {
      float4 v = p4[q];
      x[q * 4 + 0] = v.x; x[q * 4 + 1] = v.y; x[q * 4 + 2] = v.z; x[q * 4 + 3] = v.w;
    }
  }
  float mrow[16];
  float m2 = 0.f;
#pragma unroll
  for (int k = 0; k < 16; ++k) {
    float s = 0.f;
#pragma unroll
    for (int l = 0; l < 16; ++l) s += x[l] * A[k * 16 + l];
#pragma unroll
    for (int l = 0; l < 8; ++l) s += x[16 + l] * B[k * 8 + l];
    mrow[k] = s;
    m2 += s * s;
  }
  av1[j] = LOG2E * (lw[j] - 0.5f * m2);

  unsigned int buf[16];
  pack_row(mrow, buf);
  {
    uint4* dst = (uint4*)(muP + (size_t)j * 16);
#pragma unroll
    for (int q = 0; q < 4; ++q)
      dst[q] = make_uint4(buf[q * 4], buf[q * 4 + 1], buf[q * 4 + 2], buf[q * 4 + 3]);
  }
  float srow[16];
  {
    const float4* s4 = (const float4*)(sp + (size_t)j * 16);
#pragma unroll
    for (int q = 0; q < 4; ++q) {
      float4 v = s4[q];
      srow[q * 4 + 0] = LOG2E * v.x; srow[q * 4 + 1] = LOG2E * v.y;
      srow[q * 4 + 2] = LOG2E * v.z; srow[q * 4 + 3] = LOG2E * v.w;
    }
  }
  pack_row(srow, buf);
  {
    uint4* dst = (uint4*)(spT + (size_t)j * 16);
#pragma unroll
    for (int q = 0; q < 4; ++q)
      dst[q] = make_uint4(buf[q * 4], buf[q * 4 + 1], buf[q * 4 + 2], buf[q * 4 + 3]);
  }
}

// part[chunk][r] = sum over 128 tile rows t of chunk of 2^( av[t] + stat_r . tile_t )
// 32x32x16 MFMA. Tile in LDS at row stride 20 words (balanced 8-slot b128 reads).
// 3-MFMA hi/lo split. __launch_bounds__(256,4): 128-VGPR headroom so the
// compiler can keep 2-3 tiles' d-vectors in flight (software pipeline) —
// A/B vs round 7's (256,8) 64-VGPR cap.
__global__ __launch_bounds__(256, 4) void k_pass(
    const unsigned int* __restrict__ tilev,
    const unsigned int* __restrict__ statv,
    const float* __restrict__ avv,
    const float* __restrict__ psrc,
    float* __restrict__ part) {
  __shared__ __align__(16) unsigned int tl[128 * 20];
  __shared__ __align__(16) float av_l[128];
  __shared__ float sums[256];
  const int t = threadIdx.x;
  const int chunk = blockIdx.x;  // 0..63, fast
  const int sg    = blockIdx.y;  // 0..63

  // stage tile: 128 rows x 16 u32 -> LDS stride 20 (coalesced uint4 src)
  {
    const uint4* src = (const uint4*)(tilev + (size_t)chunk * 2048);
#pragma unroll
    for (int q = 0; q < 2; ++q) {
      int f = t + 256 * q;
      int row = f >> 2, s = f & 3;
      *(uint4*)(tl + row * 20 + s * 4) = src[f];
    }
  }

  if (psrc == nullptr) {
    if (t < 128) av_l[t] = avv[chunk * 128 + t];
  } else {
    const int row = t & 127, half = t >> 7;
    float s = 0.f;
    const float* p = psrc + (size_t)(half * 32) * 8192 + chunk * 128 + row;
#pragma unroll 8
    for (int c = 0; c < 32; ++c) s += p[(size_t)c * 8192];
    sums[t] = s;
    __syncthreads();
    if (t < 128) {
      float sv = sums[t] + sums[t + 128];
      av_l[t] = LOG2E * avv[chunk * 128 + t] - fast_log2(sv);
    }
  }
  __syncthreads();

  const int l = t & 63;
  const int wave = t >> 6;
  const int lr = l & 31;   // A-row / B-col / D-col selector
  const int hi = l >> 5;   // k-half selector
  const int r0 = sg * 128 + wave * 32;

  // stationary B fragments (row r0+lr, k-half hi)
  const unsigned int* brow = statv + (size_t)(r0 + lr) * 16 + hi * 4;
  const bf16x8 b_hi = *(const bf16x8*)brow;
  const bf16x8 b_lo = *(const bf16x8*)(brow + 8);

  float acc = 0.f;
#pragma unroll
  for (int tile = 0; tile < 4; ++tile) {
    const unsigned int* arow = tl + (tile * 32 + lr) * 20 + hi * 4;
    const bf16x8 a_hi = *(const bf16x8*)arow;
    const bf16x8 a_lo = *(const bf16x8*)(arow + 8);

    // C init = av[tile row]; C row = (reg&3) + 8*(reg>>2) + 4*hi
    f32x16 d;
#pragma unroll
    for (int q = 0; q < 4; ++q) {
      const f32x4 v = *(const f32x4*)(av_l + tile * 32 + 8 * q + 4 * hi);
      d[4 * q + 0] = v[0]; d[4 * q + 1] = v[1];
      d[4 * q + 2] = v[2]; d[4 * q + 3] = v[3];
    }
    d = __builtin_amdgcn_mfma_f32_32x32x16_bf16(a_hi, b_hi, d, 0, 0, 0);
    d = __builtin_amdgcn_mfma_f32_32x32x16_bf16(a_lo, b_hi, d, 0, 0, 0);
    d = __builtin_amdgcn_mfma_f32_32x32x16_bf16(a_hi, b_lo, d, 0, 0, 0);

    float e0 = fast_exp2(d[0])  + fast_exp2(d[1]);
    float e1 = fast_exp2(d[2])  + fast_exp2(d[3]);
    float e2 = fast_exp2(d[4])  + fast_exp2(d[5]);
    float e3 = fast_exp2(d[6])  + fast_exp2(d[7]);
    float e4 = fast_exp2(d[8])  + fast_exp2(d[9]);
    float e5 = fast_exp2(d[10]) + fast_exp2(d[11]);
    float e6 = fast_exp2(d[12]) + fast_exp2(d[13]);
    float e7 = fast_exp2(d[14]) + fast_exp2(d[15]);
    acc += ((e0 + e1) + (e2 + e3)) + ((e4 + e5) + (e6 + e7));
  }
  acc += __shfl_xor(acc, 32);
  if (l < 32) part[(size_t)chunk * 8192 + r0 + lr] = acc;
}

__global__ __launch_bounds__(256) void k_out(
    const float* __restrict__ part, const float* __restrict__ av1,
    float* __restrict__ out) {
  int j = blockIdx.x * 256 + threadIdx.x;
  float s = 0.f;
#pragma unroll
  for (int c = 0; c < 64; ++c) s += part[(size_t)c * 8192 + j];
  out[j] = LN2 * (av1[j] + fast_log2(s));
}

extern "C" void kernel_launch(void* const* d_in, const int* in_sizes, int n_in,
                              void* d_out, int out_size, void* d_ws, size_t ws_size,
                              hipStream_t stream) {
  const float* particles = (const float*)d_in[0];
  const float* lw        = (const float*)d_in[1];
  const float* sp        = (const float*)d_in[2];
  const float* w         = (const float*)d_in[3];
  const float* A         = (const float*)d_in[4];
  const float* B         = (const float*)d_in[5];

  float* ws = (float*)d_ws;
  unsigned int* muP = (unsigned int*)(ws + WS_MUP);
  unsigned int* spT = (unsigned int*)(ws + WS_SPT);
  float* av1  = ws + WS_AV1;
  float* p1   = ws + WS_P1;
  float* p2   = ws + WS_P2;
  float* out  = (float*)d_out;

  k_prep<<<dim3(32), dim3(256), 0, stream>>>(particles, lw, sp, A, B, muP, spT, av1);
  // pass 1: tile = mu chunks (j, av1), stationary = sp' (i) -> S1 partials per i
  k_pass<<<dim3(64, 64), dim3(256), 0, stream>>>(muP, spT, av1, nullptr, p1);
  // pass 2: tile = sp' chunks (i, av2 in prologue), stationary = mu (j)
  k_pass<<<dim3(64, 64), dim3(256), 0, stream>>>(spT, muP, w, p1, p2);
  k_out<<<dim3(32), dim3(256), 0, stream>>>(p2, av1, out);
}

// Round 9
// 47.604 us; speedup vs baseline: 1.0695x; 1.0695x over previous
//
#include <hip/hip_runtime.h>

#define LOG2E 1.44269504088896340736f
#define LN2   0.69314718055994530942f

typedef __attribute__((ext_vector_type(8))) short bf16x8;
typedef __attribute__((ext_vector_type(4))) float f32x4;
typedef __attribute__((ext_vector_type(16))) float f32x16;

// ws float offsets
#define WS_MUP  0        // 8192 x 16 u32 : packed [mu_hi(16)|mu_lo(16)] bf16
#define WS_SPT  131072   // 8192 x 16 u32 : packed [sp'_hi|sp'_lo], sp' = log2e*sp
#define WS_AV1  262144   // 8192 f32
#define WS_P1   270336   // 64 x 8192 f32 partials, pass 1
#define WS_P2   794624   // 64 x 8192 f32 partials, pass 2

__device__ __forceinline__ unsigned short bf16_rne(float x) {
  unsigned int u = __float_as_uint(x);
  u = u + 0x7FFFu + ((u >> 16) & 1u);
  return (unsigned short)(u >> 16);
}
__device__ __forceinline__ float bf16f(unsigned short h) {
  return __uint_as_float(((unsigned int)h) << 16);
}
__device__ __forceinline__ float fast_exp2(float x) {
#if __has_builtin(__builtin_amdgcn_exp2f)
  return __builtin_amdgcn_exp2f(x);
#else
  return exp2f(x);
#endif
}
__device__ __forceinline__ float fast_log2(float x) {
#if __has_builtin(__builtin_amdgcn_logf)
  return __builtin_amdgcn_logf(x);
#else
  return log2f(x);
#endif
}

__device__ __forceinline__ void pack_row(const float* v, unsigned int* buf) {
#pragma unroll
  for (int k = 0; k < 16; k += 2) {
    unsigned short h0 = bf16_rne(v[k]);
    unsigned short h1 = bf16_rne(v[k + 1]);
    float l0 = v[k] - bf16f(h0);
    float l1 = v[k + 1] - bf16f(h1);
    buf[k >> 1] = (unsigned int)h0 | ((unsigned int)h1 << 16);
    buf[8 + (k >> 1)] = (unsigned int)bf16_rne(l0) | ((unsigned int)bf16_rne(l1) << 16);
  }
}

__global__ __launch_bounds__(256) void k_prep(
    const float* __restrict__ particles, const float* __restrict__ lw,
    const float* __restrict__ sp,
    const float* __restrict__ A, const float* __restrict__ B,
    unsigned int* __restrict__ muP, unsigned int* __restrict__ spT,
    float* __restrict__ av1) {
  int j = blockIdx.x * 256 + threadIdx.x;
  float x[24];
  {
    const float4* p4 = (const float4*)(particles + (size_t)j * 24);
#pragma unroll
    for (int q = 0; q < 6; ++q) {
      float4 v = p4[q];
      x[q * 4 + 0] = v.x; x[q * 4 + 1] = v.y; x[q * 4 + 2] = v.z; x[q * 4 + 3] = v.w;
    }
  }
  float mrow[16];
  float m2 = 0.f;
#pragma unroll
  for (int k = 0; k < 16; ++k) {
    float s = 0.f;
#pragma unroll
    for (int l = 0; l < 16; ++l) s += x[l] * A[k * 16 + l];
#pragma unroll
    for (int l = 0; l < 8; ++l) s += x[16 + l] * B[k * 8 + l];
    mrow[k] = s;
    m2 += s * s;
  }
  av1[j] = LOG2E * (lw[j] - 0.5f * m2);

  unsigned int buf[16];
  pack_row(mrow, buf);
  {
    uint4* dst = (uint4*)(muP + (size_t)j * 16);
#pragma unroll
    for (int q = 0; q < 4; ++q)
      dst[q] = make_uint4(buf[q * 4], buf[q * 4 + 1], buf[q * 4 + 2], buf[q * 4 + 3]);
  }
  float srow[16];
  {
    const float4* s4 = (const float4*)(sp + (size_t)j * 16);
#pragma unroll
    for (int q = 0; q < 4; ++q) {
      float4 v = s4[q];
      srow[q * 4 + 0] = LOG2E * v.x; srow[q * 4 + 1] = LOG2E * v.y;
      srow[q * 4 + 2] = LOG2E * v.z; srow[q * 4 + 3] = LOG2E * v.w;
    }
  }
  pack_row(srow, buf);
  {
    uint4* dst = (uint4*)(spT + (size_t)j * 16);
#pragma unroll
    for (int q = 0; q < 4; ++q)
      dst[q] = make_uint4(buf[q * 4], buf[q * 4 + 1], buf[q * 4 + 2], buf[q * 4 + 3]);
  }
}

#define EXPSUM16(d, acc)                                              \
  {                                                                   \
    float e0 = fast_exp2(d[0])  + fast_exp2(d[1]);                    \
    float e1 = fast_exp2(d[2])  + fast_exp2(d[3]);                    \
    float e2 = fast_exp2(d[4])  + fast_exp2(d[5]);                    \
    float e3 = fast_exp2(d[6])  + fast_exp2(d[7]);                    \
    float e4 = fast_exp2(d[8])  + fast_exp2(d[9]);                    \
    float e5 = fast_exp2(d[10]) + fast_exp2(d[11]);                   \
    float e6 = fast_exp2(d[12]) + fast_exp2(d[13]);                   \
    float e7 = fast_exp2(d[14]) + fast_exp2(d[15]);                   \
    acc += ((e0 + e1) + (e2 + e3)) + ((e4 + e5) + (e6 + e7));         \
  }

// part[chunk][r] = sum over 128 tile rows t of chunk of 2^( av[t] + stat_r . tile_t )
// 32x32x16 MFMA, 3-MFMA hi/lo split. Each wave owns TWO stationary strips (64
// rows): the per-tile LDS reads (2 a-rows + 4 av C-init b128) are amortized
// over 2 MFMA chains -> LDS pipe/CU/pass ~3.8 us, below the VALU/trans floor.
__global__ __launch_bounds__(256, 4) void k_pass(
    const unsigned int* __restrict__ tilev,
    const unsigned int* __restrict__ statv,
    const float* __restrict__ avv,
    const float* __restrict__ psrc,
    float* __restrict__ part) {
  __shared__ __align__(16) unsigned int tl[128 * 20];
  __shared__ __align__(16) float av_l[128];
  __shared__ float sums[256];
  const int t = threadIdx.x;
  const int chunk = blockIdx.x;  // 0..63, fast
  const int sg    = blockIdx.y;  // 0..31

  // stage tile: 128 rows x 16 u32 -> LDS stride 20 (balanced b128 slots)
  {
    const uint4* src = (const uint4*)(tilev + (size_t)chunk * 2048);
#pragma unroll
    for (int q = 0; q < 2; ++q) {
      int f = t + 256 * q;
      int row = f >> 2, s = f & 3;
      *(uint4*)(tl + row * 20 + s * 4) = src[f];
    }
  }

  if (psrc == nullptr) {
    if (t < 128) av_l[t] = avv[chunk * 128 + t];
  } else {
    const int row = t & 127, half = t >> 7;
    float s = 0.f;
    const float* p = psrc + (size_t)(half * 32) * 8192 + chunk * 128 + row;
#pragma unroll 8
    for (int c = 0; c < 32; ++c) s += p[(size_t)c * 8192];
    sums[t] = s;
    __syncthreads();
    if (t < 128) {
      float sv = sums[t] + sums[t + 128];
      av_l[t] = LOG2E * avv[chunk * 128 + t] - fast_log2(sv);
    }
  }
  __syncthreads();

  const int l = t & 63;
  const int wave = t >> 6;
  const int lr = l & 31;   // A-row / B-col / D-col selector
  const int hi = l >> 5;   // k-half selector
  const int r0 = sg * 256 + wave * 64;  // wave's 64 stationary rows

  // stationary B fragments, strips 0 and 1
  const unsigned int* brow0 = statv + (size_t)(r0 + lr) * 16 + hi * 4;
  const unsigned int* brow1 = statv + (size_t)(r0 + 32 + lr) * 16 + hi * 4;
  const bf16x8 b_hi0 = *(const bf16x8*)brow0;
  const bf16x8 b_lo0 = *(const bf16x8*)(brow0 + 8);
  const bf16x8 b_hi1 = *(const bf16x8*)brow1;
  const bf16x8 b_lo1 = *(const bf16x8*)(brow1 + 8);

  float acc0 = 0.f, acc1 = 0.f;
#pragma unroll
  for (int tile = 0; tile < 4; ++tile) {
    const unsigned int* arow = tl + (tile * 32 + lr) * 20 + hi * 4;
    const bf16x8 a_hi = *(const bf16x8*)arow;
    const bf16x8 a_lo = *(const bf16x8*)(arow + 8);

    // C init = av[tile row]; C row = (reg&3) + 8*(reg>>2) + 4*hi
    const f32x4 c0 = *(const f32x4*)(av_l + tile * 32 + 0  + 4 * hi);
    const f32x4 c1 = *(const f32x4*)(av_l + tile * 32 + 8  + 4 * hi);
    const f32x4 c2 = *(const f32x4*)(av_l + tile * 32 + 16 + 4 * hi);
    const f32x4 c3 = *(const f32x4*)(av_l + tile * 32 + 24 + 4 * hi);
    f32x16 d0, d1;
#pragma unroll
    for (int e = 0; e < 4; ++e) {
      d0[e] = c0[e]; d0[4 + e] = c1[e]; d0[8 + e] = c2[e]; d0[12 + e] = c3[e];
      d1[e] = c0[e]; d1[4 + e] = c1[e]; d1[8 + e] = c2[e]; d1[12 + e] = c3[e];
    }
    d0 = __builtin_amdgcn_mfma_f32_32x32x16_bf16(a_hi, b_hi0, d0, 0, 0, 0);
    d0 = __builtin_amdgcn_mfma_f32_32x32x16_bf16(a_lo, b_hi0, d0, 0, 0, 0);
    d0 = __builtin_amdgcn_mfma_f32_32x32x16_bf16(a_hi, b_lo0, d0, 0, 0, 0);
    d1 = __builtin_amdgcn_mfma_f32_32x32x16_bf16(a_hi, b_hi1, d1, 0, 0, 0);
    d1 = __builtin_amdgcn_mfma_f32_32x32x16_bf16(a_lo, b_hi1, d1, 0, 0, 0);
    d1 = __builtin_amdgcn_mfma_f32_32x32x16_bf16(a_hi, b_lo1, d1, 0, 0, 0);

    EXPSUM16(d0, acc0)
    EXPSUM16(d1, acc1)
  }
  acc0 += __shfl_xor(acc0, 32);
  acc1 += __shfl_xor(acc1, 32);
  if (l < 32) part[(size_t)chunk * 8192 + r0 + lr] = acc0;
  else        part[(size_t)chunk * 8192 + r0 + 32 + lr] = acc1;
}

__global__ __launch_bounds__(256) void k_out(
    const float* __restrict__ part, const float* __restrict__ av1,
    float* __restrict__ out) {
  int j = blockIdx.x * 256 + threadIdx.x;
  float s = 0.f;
#pragma unroll
  for (int c = 0; c < 64; ++c) s += part[(size_t)c * 8192 + j];
  out[j] = LN2 * (av1[j] + fast_log2(s));
}

extern "C" void kernel_launch(void* const* d_in, const int* in_sizes, int n_in,
                              void* d_out, int out_size, void* d_ws, size_t ws_size,
                              hipStream_t stream) {
  const float* particles = (const float*)d_in[0];
  const float* lw        = (const float*)d_in[1];
  const float* sp        = (const float*)d_in[2];
  const float* w         = (const float*)d_in[3];
  const float* A         = (const float*)d_in[4];
  const float* B         = (const float*)d_in[5];

  float* ws = (float*)d_ws;
  unsigned int* muP = (unsigned int*)(ws + WS_MUP);
  unsigned int* spT = (unsigned int*)(ws + WS_SPT);
  float* av1  = ws + WS_AV1;
  float* p1   = ws + WS_P1;
  float* p2   = ws + WS_P2;
  float* out  = (float*)d_out;

  k_prep<<<dim3(32), dim3(256), 0, stream>>>(particles, lw, sp, A, B, muP, spT, av1);
  // pass 1: tile = mu chunks (j, av1), stationary = sp' (i) -> S1 partials per i
  k_pass<<<dim3(64, 32), dim3(256), 0, stream>>>(muP, spT, av1, nullptr, p1);
  // pass 2: tile = sp' chunks (i, av2 in prologue), stationary = mu (j)
  k_pass<<<dim3(64, 32), dim3(256), 0, stream>>>(spT, muP, w, p1, p2);
  k_out<<<dim3(32), dim3(256), 0, stream>>>(p2, av1, out);
}